// Round 3
// baseline (661.983 us; speedup 1.0000x reference)
//
#include <hip/hip_runtime.h>
#include <hip/hip_bf16.h>

// Problem constants (QuantTokenPredictor): h (4,2048,256) f32, w (16384,256) f32
// out (4,2048,16384) f32 distances.
static constexpr int M_ = 8192;    // B*S
static constexpr int N_ = 16384;   // NUM_TOKS
static constexpr int K_ = 256;     // TOK_DIM
static constexpr int BM = 128, BN = 128, BK = 64;

typedef __attribute__((ext_vector_type(4))) float f32x4;
typedef __attribute__((ext_vector_type(8))) short bf16x8;

__device__ __forceinline__ ushort f2bf(float f) {
  __hip_bfloat16 b = __float2bfloat16(f);
  return __builtin_bit_cast(ushort, b);
}

// One wave per 256-element row: cast f32 -> bf16 and compute fp32 sum of squares.
__global__ __launch_bounds__(256) void cast_rows_k(
    const float* __restrict__ in, ushort* __restrict__ outb,
    float* __restrict__ sq)
{
  const int row  = blockIdx.x * 4 + (threadIdx.x >> 6);
  const int lane = threadIdx.x & 63;
  const float4 v = reinterpret_cast<const float4*>(in)[(size_t)row * 64 + lane];
  ushort4 o;
  o.x = f2bf(v.x); o.y = f2bf(v.y); o.z = f2bf(v.z); o.w = f2bf(v.w);
  reinterpret_cast<ushort4*>(outb)[(size_t)row * 64 + lane] = o;
  float s = v.x * v.x + v.y * v.y + v.z * v.z + v.w * v.w;
  #pragma unroll
  for (int off = 32; off > 0; off >>= 1) s += __shfl_down(s, off, 64);
  if (lane == 0) sq[row] = s;
}

// 128x128 tile, BK=64, 4 waves (2x2 of 64x64), global_load_lds staging,
// mfma_f32_16x16x32_bf16, fused sqrt(max(h2 - 2*cross + w2, 0)) epilogue.
__global__ __launch_bounds__(256) void dist_gemm_k(
    const ushort* __restrict__ A,    // M x K bf16 (h)
    const ushort* __restrict__ Bm,   // N x K bf16 (w)
    const float* __restrict__ h2,    // M
    const float* __restrict__ w2,    // N
    float* __restrict__ C)           // M x N f32
{
  __shared__ ushort As[BM * BK];     // [128][64] bf16, 16 KB
  __shared__ ushort Bs[BN * BK];

  const int tid  = threadIdx.x;
  const int lane = tid & 63;
  const int wid  = tid >> 6;

  // XCD-aware swizzle; grid = 8192, divisible by 8 -> bijective.
  const int nwg = gridDim.x;
  const int cpx = nwg >> 3;
  const int bid = (blockIdx.x & 7) * cpx + (blockIdx.x >> 3);

  const int nbn  = N_ / BN;          // 128
  const int brow = (bid / nbn) * BM;
  const int bcol = (bid % nbn) * BN;

  const int wrow = (wid >> 1) * 64;  // wave sub-tile origin inside block tile
  const int wcol = (wid & 1) * 64;

  f32x4 acc[4][4] = {};              // 4x4 fragments of 16x16

  // Staging: tiles are 1024 chunks of 16B; wave handles 64 chunks/issue.
  const int q0 = wid * 64 + lane;

  for (int kt = 0; kt < K_ / BK; ++kt) {
    #pragma unroll
    for (int it = 0; it < 4; ++it) {
      const int q  = it * 256 + q0;        // 16B-chunk id in [0,1024)
      const int r  = q >> 3;               // tile row
      const int ce = (q & 7) * 8;          // ushort col offset within row
      const ushort* srcA = A  + (size_t)(brow + r) * K_ + kt * BK + ce;
      const ushort* srcB = Bm + (size_t)(bcol + r) * K_ + kt * BK + ce;
      ushort* dstA = &As[(it * 4 + wid) * 512];   // wave-uniform base
      ushort* dstB = &Bs[(it * 4 + wid) * 512];
      __builtin_amdgcn_global_load_lds(
          (const __attribute__((address_space(1))) unsigned int*)srcA,
          (__attribute__((address_space(3))) unsigned int*)dstA, 16, 0, 0);
      __builtin_amdgcn_global_load_lds(
          (const __attribute__((address_space(1))) unsigned int*)srcB,
          (__attribute__((address_space(3))) unsigned int*)dstB, 16, 0, 0);
    }
    __syncthreads();   // drains vmcnt(0): staged data visible

    #pragma unroll
    for (int kk = 0; kk < 2; ++kk) {
      bf16x8 af[4], bfr[4];
      const int kb = kk * 32 + ((lane >> 4) * 8);   // k offset for this lane
      #pragma unroll
      for (int i = 0; i < 4; ++i) {
        const int ar = wrow + i * 16 + (lane & 15);
        af[i]  = *reinterpret_cast<const bf16x8*>(&As[ar * BK + kb]);
        const int br = wcol + i * 16 + (lane & 15);
        bfr[i] = *reinterpret_cast<const bf16x8*>(&Bs[br * BK + kb]);
      }
      #pragma unroll
      for (int i = 0; i < 4; ++i)
        #pragma unroll
        for (int j = 0; j < 4; ++j)
          acc[i][j] = __builtin_amdgcn_mfma_f32_16x16x32_bf16(
              af[i], bfr[j], acc[i][j], 0, 0, 0);
    }
    __syncthreads();   // protect LDS before next stage
  }

  // Epilogue: C/D layout col = lane&15, row = (lane>>4)*4 + reg  [m89/m91]
  const int cl   = lane & 15;
  const int row0 = brow + wrow + ((lane >> 4) << 2);
  const int col0 = bcol + wcol;
  float h2v[16];
  #pragma unroll
  for (int i = 0; i < 4; ++i)
    #pragma unroll
    for (int r = 0; r < 4; ++r)
      h2v[i * 4 + r] = h2[row0 + i * 16 + r];

  #pragma unroll
  for (int j = 0; j < 4; ++j) {
    const int col  = col0 + j * 16 + cl;
    const float wc = w2[col];
    #pragma unroll
    for (int i = 0; i < 4; ++i) {
      const int row = row0 + i * 16;
      #pragma unroll
      for (int r = 0; r < 4; ++r) {
        const float v = h2v[i * 4 + r] - 2.0f * acc[i][j][r] + wc;
        C[(size_t)(row + r) * N_ + col] = sqrtf(fmaxf(v, 0.0f));
      }
    }
  }
}

// Safety-net fallback if workspace is too small (pure fp32, slow but correct).
__global__ void naive_dist_k(const float* __restrict__ h,
                             const float* __restrict__ w,
                             float* __restrict__ C)
{
  const size_t idx = (size_t)blockIdx.x * 256 + threadIdx.x;
  const int m = (int)(idx / N_);
  const int n = (int)(idx % N_);
  const float* hr = h + (size_t)m * K_;
  const float* wr = w + (size_t)n * K_;
  float dot = 0.f, hh = 0.f, ww = 0.f;
  for (int k = 0; k < K_; ++k) {
    const float a = hr[k], b = wr[k];
    dot += a * b; hh += a * a; ww += b * b;
  }
  C[idx] = sqrtf(fmaxf(hh - 2.0f * dot + ww, 0.0f));
}

extern "C" void kernel_launch(void* const* d_in, const int* in_sizes, int n_in,
                              void* d_out, int out_size, void* d_ws, size_t ws_size,
                              hipStream_t stream) {
  const float* h = (const float*)d_in[0];
  const float* w = (const float*)d_in[1];
  float* out = (float*)d_out;

  const size_t need = (size_t)M_ * K_ * 2 + (size_t)N_ * K_ * 2
                    + (size_t)M_ * 4 + (size_t)N_ * 4;
  if (ws_size < need) {
    naive_dist_k<<<(int)(((size_t)M_ * N_) / 256), 256, 0, stream>>>(h, w, out);
    return;
  }

  ushort* hb = (ushort*)d_ws;
  ushort* wb = hb + (size_t)M_ * K_;
  float*  s1 = (float*)(wb + (size_t)N_ * K_);   // h2: M floats
  float*  s2 = s1 + M_;                          // w2: N floats

  cast_rows_k<<<M_ / 4, 256, 0, stream>>>(h, hb, s1);
  cast_rows_k<<<N_ / 4, 256, 0, stream>>>(w, wb, s2);
  dist_gemm_k<<<(M_ / BM) * (N_ / BN), 256, 0, stream>>>(hb, wb, s1, s2, out);
}